// Round 4
// baseline (533.824 us; speedup 1.0000x reference)
//
#include <hip/hip_runtime.h>
#include <hip/hip_bf16.h>

// ColdPrompt: task_specific[u,b,o] = sum_i prompt[b,i]*W_spec[u,i,o] + b_spec[u,o]
//             mean_emb[b,d] = mean_p weight[b,p,d]
// Shapes: B=256, P=4, D=768, IN=3072, U=32.
// Memory-bound on W_spec (302 MB fp32): BM=256 so W is read from HBM exactly once.

#define U_CNT  32
#define BROWS  256
#define DDIM   768
#define KDIM   3072
#define BK     32
#define BN     64
#define NT     12          // DDIM / BN
#define KITERS 96          // KDIM / BK
#define WSTRIDE 40         // padded k-stride (elems) for transposed W tile in LDS

typedef float  f32x4 __attribute__((ext_vector_type(4)));
typedef __bf16 bf16x8 __attribute__((ext_vector_type(8)));

__global__ __launch_bounds__(256, 3) void coldprompt_gemm(
    const float* __restrict__ A,      // [256][3072] = weight reshaped
    const float* __restrict__ Wsp,    // [32][3072][768]
    const float* __restrict__ bsp,    // [32][768]
    float* __restrict__ out)          // [8192][768]
{
    // Only W staged in LDS (transposed to [n][k]); A is L2/L3-resident, goes
    // straight to registers (each A element used by exactly one wave here).
    __shared__ __align__(16) __bf16 wT[2][BN * WSTRIDE];

    const int tid  = threadIdx.x;
    const int lane = tid & 63;
    const int wave = tid >> 6;          // 0..3, wave-tile 64(m) x 64(n)
    const int bid  = blockIdx.x;
    const int u    = bid / NT;
    const int n0   = (bid % NT) * BN;

    const float* __restrict__ Wu = Wsp + (size_t)u * (KDIM * DDIM);

    // W staging: thread t covers d = t&63 (one LDS row), k = (t>>6)*8 .. +8
    const int sd = tid & 63;
    const int sk = (tid >> 6) * 8;

    // MFMA fragment indexing (16x16x32 bf16): lane holds 8 consecutive k
    const int fcol = lane & 15;
    const int fk8  = (lane >> 4) * 8;

    f32x4 acc[4][4];
#pragma unroll
    for (int i = 0; i < 4; ++i)
#pragma unroll
        for (int j = 0; j < 4; ++j)
            acc[i][j] = (f32x4){0.f, 0.f, 0.f, 0.f};

    // ---- prologue: stage k-block 0 into buffer 0 ----
    {
        const float* src = Wu + (size_t)sk * DDIM + n0 + sd;
        bf16x8 wv;
#pragma unroll
        for (int j = 0; j < 8; ++j) wv[j] = (__bf16)src[(size_t)j * DDIM];  // coalesced 256B per j
        *(bf16x8*)&wT[0][sd * WSTRIDE + sk] = wv;   // 16B-aligned ds_write_b128
    }

    const float* __restrict__ arow = A + (size_t)(wave * 64 + fcol) * KDIM + fk8;

    int cur = 0;
    for (int kb = 0; kb < KITERS; ++kb) {
        __syncthreads();   // prev writes to wT[cur] visible; prev reads of wT[cur^1] done

        // prefetch next W k-block into registers (drains after MFMA block)
        float wreg[8];
        if (kb + 1 < KITERS) {
            const float* src = Wu + (size_t)((kb + 1) * BK + sk) * DDIM + n0 + sd;
#pragma unroll
            for (int j = 0; j < 8; ++j) wreg[j] = src[(size_t)j * DDIM];
        }

        // A fragments straight from global (fp32 -> bf16 in-reg)
        bf16x8 afrag[4];
#pragma unroll
        for (int mf = 0; mf < 4; ++mf) {
            const float* ap = arow + (size_t)(mf * 16) * KDIM + kb * BK;
            f32x4 a0 = *(const f32x4*)ap;
            f32x4 a1 = *(const f32x4*)(ap + 4);
#pragma unroll
            for (int j = 0; j < 4; ++j) {
                afrag[mf][j]     = (__bf16)a0[j];
                afrag[mf][4 + j] = (__bf16)a1[j];
            }
        }

        // W fragments from LDS (transposed rows: 8 consecutive k -> ds_read_b128)
        bf16x8 wfrag[4];
#pragma unroll
        for (int nf = 0; nf < 4; ++nf)
            wfrag[nf] = *(bf16x8*)&wT[cur][(nf * 16 + fcol) * WSTRIDE + fk8];

#pragma unroll
        for (int mf = 0; mf < 4; ++mf)
#pragma unroll
            for (int nf = 0; nf < 4; ++nf)
                acc[mf][nf] = __builtin_amdgcn_mfma_f32_16x16x32_bf16(
                    afrag[mf], wfrag[nf], acc[mf][nf], 0, 0, 0);

        // write next tile into the other buffer (race-free: next read is after
        // next iteration's barrier)
        if (kb + 1 < KITERS) {
            bf16x8 wv;
#pragma unroll
            for (int j = 0; j < 8; ++j) wv[j] = (__bf16)wreg[j];
            *(bf16x8*)&wT[cur ^ 1][sd * WSTRIDE + sk] = wv;
        }
        cur ^= 1;
    }

    // ---- epilogue: bias + store. C/D layout: col=lane&15, row=(lane>>4)*4+j ----
#pragma unroll
    for (int nf = 0; nf < 4; ++nf) {
        const int col  = n0 + nf * 16 + fcol;
        const float bias = bsp[u * DDIM + col];
#pragma unroll
        for (int mf = 0; mf < 4; ++mf) {
            const int rowb = wave * 64 + mf * 16 + ((lane >> 4) * 4);
            float* op = out + (size_t)(u * BROWS + rowb) * DDIM + col;
#pragma unroll
            for (int j = 0; j < 4; ++j)
                op[(size_t)j * DDIM] = acc[mf][nf][j] + bias;
        }
    }
}

__global__ void coldprompt_mean(const float* __restrict__ w, float* __restrict__ out) {
    const int b = blockIdx.x;            // 0..255
    const int d = threadIdx.x * 4;       // block 192 -> covers 768
    const float* p = w + (size_t)b * (4 * DDIM) + d;
    f32x4 s0 = *(const f32x4*)p;
    f32x4 s1 = *(const f32x4*)(p + DDIM);
    f32x4 s2 = *(const f32x4*)(p + 2 * DDIM);
    f32x4 s3 = *(const f32x4*)(p + 3 * DDIM);
    f32x4 m = (s0 + s1 + s2 + s3) * 0.25f;
    *(f32x4*)(out + (size_t)b * DDIM + d) = m;
}

extern "C" void kernel_launch(void* const* d_in, const int* in_sizes, int n_in,
                              void* d_out, int out_size, void* d_ws, size_t ws_size,
                              hipStream_t stream) {
    const float* weight = (const float*)d_in[0];   // [256][4][768] == [256][3072]
    const float* Wsp    = (const float*)d_in[1];   // [32][3072][768]
    const float* bsp    = (const float*)d_in[2];   // [32][768]
    float* out = (float*)d_out;

    coldprompt_gemm<<<U_CNT * NT, 256, 0, stream>>>(weight, Wsp, bsp, out);

    float* mean_out = out + (size_t)U_CNT * BROWS * DDIM;   // offset 6,291,456
    coldprompt_mean<<<BROWS, 192, 0, stream>>>(weight, mean_out);
}

// Round 5
// 526.069 us; speedup vs baseline: 1.0147x; 1.0147x over previous
//
#include <hip/hip_runtime.h>
#include <hip/hip_bf16.h>

// ColdPrompt: task_specific[u,b,o] = sum_i prompt[b,i]*W_spec[u,i,o] + b_spec[u,o]
//             mean_emb[b,d] = mean_p weight[b,p,d]
// R4 diagnosis: 384 wgs = 1.5 blocks/CU = 15.8% occupancy, latency-bound
// (241us, 790 GB/s, MfmaUtil 6.3%). Fix: BM=128 (768 wgs, 3 blocks/CU),
// 2-deep W prefetch pipeline, XCD-pair swizzle so m-siblings share L2.

#define U_CNT  32
#define BROWS  256
#define DDIM   768
#define KDIM   3072
#define BK     32
#define BM     128
#define MT     2            // BROWS / BM
#define BN     64
#define NT     12           // DDIM / BN
#define KITERS 96           // KDIM / BK
#define WSTRIDE 40          // padded k-stride (elems) for transposed W tile

typedef float  f32x4 __attribute__((ext_vector_type(4)));
typedef __bf16 bf16x8 __attribute__((ext_vector_type(8)));

__global__ __launch_bounds__(256, 3) void coldprompt_gemm(
    const float* __restrict__ A,      // [256][3072]
    const float* __restrict__ Wsp,    // [32][3072][768]
    const float* __restrict__ bsp,    // [32][768]
    float* __restrict__ out)          // [8192][768]
{
    __shared__ __align__(16) __bf16 wT[2][BN * WSTRIDE];

    const int tid  = threadIdx.x;
    const int lane = tid & 63;
    const int wave = tid >> 6;          // 0..3, m-split: wave-tile 32x64

    // XCD-pair swizzle: logical pair i = (u,nt) has mt=0,1 siblings reading the
    // SAME W tile stream. Map both to the same XCD (bid%8) so the second is an
    // L2 hit: slot = (i%8) + 8*(2*(i/8) + mt). Inverse below. Bijective: 768
    // slots = 8 XCDs x 48 pairs x 2.
    const int bid = blockIdx.x;
    const int x   = bid & 7;
    const int jj  = bid >> 3;                 // 0..95 within XCD
    const int i   = ((jj >> 1) << 3) + x;     // logical pair 0..383
    const int mt  = jj & 1;
    const int u   = i / NT;
    const int nt  = i - u * NT;
    const int n0  = nt * BN;
    const int m0  = mt * BM;

    const float* __restrict__ Wu = Wsp + (size_t)u * (KDIM * DDIM) + n0;

    // W staging map: thread t covers col sd = t&63, k-rows sk..sk+7
    const int sd = tid & 63;
    const int sk = (tid >> 6) * 8;

    // MFMA fragment indexing (16x16x32 bf16)
    const int fcol = lane & 15;
    const int fk8  = (lane >> 4) * 8;

    f32x4 acc[2][4];
#pragma unroll
    for (int a = 0; a < 2; ++a)
#pragma unroll
        for (int b = 0; b < 4; ++b)
            acc[a][b] = (f32x4){0.f, 0.f, 0.f, 0.f};

    // Two named reg-sets (static indexing only — avoid scratch). W(k) lives in
    // set (k&1): A=even, B=odd. stage(k) issued 3 iters before its LDS write,
    // so 8 loads/set stay in flight ~2 full iterations (>> 900cy HBM latency).
    float rgA[8], rgB[8];

#define STAGE(kb, rg) do {                                                  \
    const float* s_ = Wu + (size_t)((kb) * BK + sk) * DDIM + sd;            \
    _Pragma("unroll") for (int q = 0; q < 8; ++q)                           \
        rg[q] = s_[(size_t)q * DDIM];                                       \
} while (0)

#define WWRITE(rg, buf) do {                                                \
    bf16x8 wv_;                                                             \
    _Pragma("unroll") for (int q = 0; q < 8; ++q) wv_[q] = (__bf16)rg[q];   \
    *(bf16x8*)&wT[buf][sd * WSTRIDE + sk] = wv_;                            \
} while (0)

    // prologue: W0 -> buf0; W1 in rgB; W2 in rgA (both in flight)
    STAGE(0, rgA);
    STAGE(1, rgB);
    WWRITE(rgA, 0);
    STAGE(2, rgA);

    const float* __restrict__ arow = A + (size_t)(m0 + wave * 32 + fcol) * KDIM + fk8;

    // iter kb: read buf(kb&1); write W(kb+1) from RD -> buf((kb+1)&1);
    //          refill RD with stage(kb+3).
#define ITER(kb, RD, buf) do {                                              \
    __syncthreads();                                                        \
    bf16x8 af_[2];                                                          \
    _Pragma("unroll") for (int mf = 0; mf < 2; ++mf) {                      \
        const float* ap = arow + (size_t)(mf * 16) * KDIM + (kb) * BK;      \
        f32x4 a0 = *(const f32x4*)ap;                                       \
        f32x4 a1 = *(const f32x4*)(ap + 4);                                 \
        _Pragma("unroll") for (int q = 0; q < 4; ++q) {                     \
            af_[mf][q]     = (__bf16)a0[q];                                 \
            af_[mf][4 + q] = (__bf16)a1[q];                                 \
        }                                                                   \
    }                                                                       \
    bf16x8 wf_[4];                                                          \
    _Pragma("unroll") for (int nf = 0; nf < 4; ++nf)                        \
        wf_[nf] = *(bf16x8*)&wT[buf][(nf * 16 + fcol) * WSTRIDE + fk8];     \
    _Pragma("unroll") for (int mf = 0; mf < 2; ++mf)                        \
        _Pragma("unroll") for (int nf = 0; nf < 4; ++nf)                    \
            acc[mf][nf] = __builtin_amdgcn_mfma_f32_16x16x32_bf16(          \
                af_[mf], wf_[nf], acc[mf][nf], 0, 0, 0);                    \
    if ((kb) + 1 < KITERS) WWRITE(RD, (buf) ^ 1);                           \
    if ((kb) + 3 < KITERS) STAGE((kb) + 3, RD);                             \
} while (0)

    for (int kb = 0; kb < KITERS; kb += 2) {
        ITER(kb,     rgB, 0);
        ITER(kb + 1, rgA, 1);
    }
#undef ITER
#undef STAGE
#undef WWRITE

    // epilogue: bias + store. C/D layout: col=lane&15, row=(lane>>4)*4+q
#pragma unroll
    for (int nf = 0; nf < 4; ++nf) {
        const int col  = n0 + nf * 16 + fcol;
        const float bias = bsp[u * DDIM + col];
#pragma unroll
        for (int mf = 0; mf < 2; ++mf) {
            const int rowb = m0 + wave * 32 + mf * 16 + ((lane >> 4) * 4);
            float* op = out + (size_t)(u * BROWS + rowb) * DDIM + col;
#pragma unroll
            for (int q = 0; q < 4; ++q)
                op[(size_t)q * DDIM] = acc[mf][nf][q] + bias;
        }
    }
}

__global__ void coldprompt_mean(const float* __restrict__ w, float* __restrict__ out) {
    const int b = blockIdx.x;
    const int d = threadIdx.x * 4;
    const float* p = w + (size_t)b * (4 * DDIM) + d;
    f32x4 s0 = *(const f32x4*)p;
    f32x4 s1 = *(const f32x4*)(p + DDIM);
    f32x4 s2 = *(const f32x4*)(p + 2 * DDIM);
    f32x4 s3 = *(const f32x4*)(p + 3 * DDIM);
    f32x4 m = (s0 + s1 + s2 + s3) * 0.25f;
    *(f32x4*)(out + (size_t)b * DDIM + d) = m;
}

extern "C" void kernel_launch(void* const* d_in, const int* in_sizes, int n_in,
                              void* d_out, int out_size, void* d_ws, size_t ws_size,
                              hipStream_t stream) {
    const float* weight = (const float*)d_in[0];
    const float* Wsp    = (const float*)d_in[1];
    const float* bsp    = (const float*)d_in[2];
    float* out = (float*)d_out;

    coldprompt_gemm<<<U_CNT * NT * MT, 256, 0, stream>>>(weight, Wsp, bsp, out);

    float* mean_out = out + (size_t)U_CNT * BROWS * DDIM;
    coldprompt_mean<<<BROWS, 192, 0, stream>>>(weight, mean_out);
}